// Round 1
// baseline (226.863 us; speedup 1.0000x reference)
//
#include <hip/hip_runtime.h>

typedef unsigned short u16;
typedef unsigned int   u32;
typedef __attribute__((ext_vector_type(8))) short bf16x8;  // 8 bf16 in 4 VGPRs
typedef __attribute__((ext_vector_type(4))) float f32x4;

__device__ inline u16 f2bf(float f) {
  u32 u = __builtin_bit_cast(u32, f);
  u = (u + 0x7FFFu + ((u >> 16) & 1u)) >> 16;   // RNE
  return (u16)u;
}

// ---------------------------------------------------------------------------
// Weight transpose: Wt[z][n][k] = W[z][k][n], fp32 -> bf16. grid (8,8,10).
// ---------------------------------------------------------------------------
struct TPtrs { const float* p[10]; };

__global__ __launch_bounds__(256) void transposeW(TPtrs ptrs, u16* __restrict__ out) {
  __shared__ u16 ts[64][65];                      // +1 pad breaks bank conflicts
  const float* in = ptrs.p[blockIdx.z];
  u16* o = out + (size_t)blockIdx.z * 262144;
  const int t = threadIdx.x;
  const int k0 = blockIdx.y * 64, n0 = blockIdx.x * 64;
  for (int pp = 0; pp < 16; ++pp) {
    int id = t + 256 * pp; int r = id >> 6, c = id & 63;
    ts[r][c] = f2bf(in[(size_t)(k0 + r) * 512 + n0 + c]);
  }
  __syncthreads();
  for (int pp = 0; pp < 16; ++pp) {
    int id = t + 256 * pp; int r = id >> 6, c = id & 63;
    o[(size_t)(n0 + r) * 512 + k0 + c] = ts[c][r];
  }
}

// ---------------------------------------------------------------------------
// GEMM: C[M x 512] = A[M x 512] @ Bt^T + bias.  Bt is (N=512, K=512) row-major
// bf16 (pre-transposed weight).  BM=BN=64, BK=32, 4 waves (2x2), wave=32x32.
// grid = (8, M/64).  TIN/TOUT in {float, u16(bf16)}.
// ---------------------------------------------------------------------------
template <typename TIN, typename TOUT>
__global__ __launch_bounds__(256) void gemm_bt(
    const TIN* __restrict__ A, const u16* __restrict__ Bt,
    const float* __restrict__ bias, TOUT* __restrict__ C) {
  const int t = threadIdx.x, wid = t >> 6, lane = t & 63;
  const int lg = lane >> 4, ln = lane & 15;
  const int wr = wid >> 1, wc = wid & 1;
  const int m0 = blockIdx.y * 64, n0 = blockIdx.x * 64;

  __shared__ u16 A_s[64][32];
  __shared__ u16 B_s[64][32];

  f32x4 acc[2][2];
  for (int i = 0; i < 2; ++i)
    for (int j = 0; j < 2; ++j)
      for (int r = 0; r < 4; ++r) acc[i][j][r] = 0.0f;

  for (int k0 = 0; k0 < 512; k0 += 32) {
    __syncthreads();
    {
      const int row = t >> 2, ch = t & 3;   // 64 rows x 4 chunks of 8 elems
      if constexpr (sizeof(TIN) == 4) {
        const float* src = &A[(size_t)(m0 + row) * 512 + k0 + ch * 8];
        float4 f0 = *(const float4*)(src);
        float4 f1 = *(const float4*)(src + 4);
        alignas(16) u16 tmp[8] = {f2bf(f0.x), f2bf(f0.y), f2bf(f0.z), f2bf(f0.w),
                                  f2bf(f1.x), f2bf(f1.y), f2bf(f1.z), f2bf(f1.w)};
        *(uint4*)&A_s[row][ch * 8] = *(const uint4*)tmp;
      } else {
        *(uint4*)&A_s[row][ch * 8] =
            *(const uint4*)&A[(size_t)(m0 + row) * 512 + k0 + ch * 8];
      }
      *(uint4*)&B_s[row][ch * 8] =
          *(const uint4*)&Bt[(size_t)(n0 + row) * 512 + k0 + ch * 8];
    }
    __syncthreads();

    bf16x8 af[2], bfr[2];
    for (int mi = 0; mi < 2; ++mi)
      af[mi] = *(const bf16x8*)&A_s[wr * 32 + mi * 16 + ln][lg * 8];
    for (int ni = 0; ni < 2; ++ni)
      bfr[ni] = *(const bf16x8*)&B_s[wc * 32 + ni * 16 + ln][lg * 8];
    for (int mi = 0; mi < 2; ++mi)
      for (int ni = 0; ni < 2; ++ni)
        acc[mi][ni] = __builtin_amdgcn_mfma_f32_16x16x32_bf16(
            af[mi], bfr[ni], acc[mi][ni], 0, 0, 0);
  }

  for (int ni = 0; ni < 2; ++ni) {
    const int col = n0 + wc * 32 + ni * 16 + ln;
    const float bv = bias[col];
    for (int mi = 0; mi < 2; ++mi) {
      for (int r = 0; r < 4; ++r) {
        const int row = m0 + wr * 32 + mi * 16 + 4 * lg + r;
        const float val = acc[mi][ni][r] + bv;
        if constexpr (sizeof(TOUT) == 4) C[(size_t)row * 512 + col] = val;
        else                             C[(size_t)row * 512 + col] = f2bf(val);
      }
    }
  }
}

// ---------------------------------------------------------------------------
// Flash attention over contiguous (2048,64) head blocks.
// S = (Q K^T + Qf Kf^T) * scale ; online softmax ; O = P V.
// grid (32 q-tiles, 16 bh), 256 threads = 4 waves x 16 Q-rows.
// ---------------------------------------------------------------------------
__global__ __launch_bounds__(256) void attn_kernel(
    const u16* __restrict__ q2, const u16* __restrict__ k2,
    const u16* __restrict__ qf2, const u16* __restrict__ kf2,
    const u16* __restrict__ v1, u16* __restrict__ att_out) {
  const int bh = blockIdx.y;
  const size_t base = (size_t)(bh >> 3) * 1048576 + (size_t)(bh & 7) * 131072;
  const u16* Q  = q2  + base;
  const u16* K  = k2  + base;
  const u16* Qf = qf2 + base;
  const u16* Kf = kf2 + base;
  const u16* V  = v1  + base;
  u16* O = att_out + base;

  const int t = threadIdx.x, wid = t >> 6, lane = t & 63;
  const int lg = lane >> 4, ln = lane & 15;
  const int q0 = blockIdx.x * 64;
  const int r0 = q0 + wid * 16;          // this wave's 16 Q rows

  __shared__ u16 K_s[64][64];            // cols XOR-swizzled by (row&7)*8
  __shared__ u16 Kf_s[64][64];
  __shared__ u16 Vt_s[64][64];           // Vt[d][m] = V[m][d], swizzled
  __shared__ u16 P_s[4][16][64];         // per-wave P tile, swizzled

  bf16x8 aq[4];                          // Q|Qf frags, k-chunks of 32
  {
    const int row = r0 + ln;
    aq[0] = *(const bf16x8*)&Q [row * 64 +  0 + lg * 8];
    aq[1] = *(const bf16x8*)&Q [row * 64 + 32 + lg * 8];
    aq[2] = *(const bf16x8*)&Qf[row * 64 +  0 + lg * 8];
    aq[3] = *(const bf16x8*)&Qf[row * 64 + 32 + lg * 8];
  }

  f32x4 oacc[4];
  for (int i = 0; i < 4; ++i)
    for (int r = 0; r < 4; ++r) oacc[i][r] = 0.0f;
  float m_run[4], l_run[4];
  for (int r = 0; r < 4; ++r) { m_run[r] = -1e30f; l_run[r] = 0.0f; }

  const float scale = 0.08838834764831845f;   // 1/sqrt(2*64)

  for (int kt = 0; kt < 32; ++kt) {
    const int kbase = kt * 64;
    __syncthreads();                      // prev-iter LDS reads done
    // ---- stage K, Kf (row-major, swizzled cols) ----
    for (int pp = 0; pp < 2; ++pp) {
      int id = t + 256 * pp; int row = id >> 3, ch = id & 7;
      int sw = ch ^ (row & 7);
      *(uint4*)&K_s [row][sw * 8] = *(const uint4*)&K [(size_t)(kbase + row) * 64 + ch * 8];
      *(uint4*)&Kf_s[row][sw * 8] = *(const uint4*)&Kf[(size_t)(kbase + row) * 64 + ch * 8];
    }
    // ---- stage V transposed: lane m = lane id, conflict-free writes ----
    for (int pp = 0; pp < 2; ++pp) {
      int m = t & 63; int dc = (t >> 6) + 4 * pp;
      uint4 raw = *(const uint4*)&V[(size_t)(kbase + m) * 64 + dc * 8];
      const u16* e = (const u16*)&raw;
      #pragma unroll
      for (int i = 0; i < 8; ++i) {
        int d = dc * 8 + i;
        Vt_s[d][m ^ ((d & 7) * 8)] = e[i];
      }
    }
    __syncthreads();

    // ---- S = (Q K^T + Qf Kf^T) ----
    f32x4 s[4];
    #pragma unroll
    for (int cf = 0; cf < 4; ++cf) {
      f32x4 a;
      for (int r = 0; r < 4; ++r) a[r] = 0.0f;
      const int n = cf * 16 + ln;         // K row within tile
      const int swz = (n & 7) * 8;
      #pragma unroll
      for (int ck = 0; ck < 2; ++ck) {
        bf16x8 bk = *(const bf16x8*)&K_s[n][(ck * 32 + lg * 8) ^ swz];
        a = __builtin_amdgcn_mfma_f32_16x16x32_bf16(aq[ck], bk, a, 0, 0, 0);
      }
      #pragma unroll
      for (int ck = 0; ck < 2; ++ck) {
        bf16x8 bk = *(const bf16x8*)&Kf_s[n][(ck * 32 + lg * 8) ^ swz];
        a = __builtin_amdgcn_mfma_f32_16x16x32_bf16(aq[2 + ck], bk, a, 0, 0, 0);
      }
      s[cf] = a;
    }

    // ---- online softmax (row = 4*lg + r, spread over 16 lanes) ----
    float pmax[4], psum[4];
    #pragma unroll
    for (int r = 0; r < 4; ++r)
      pmax[r] = fmaxf(fmaxf(s[0][r], s[1][r]), fmaxf(s[2][r], s[3][r])) * scale;
    #pragma unroll
    for (int off = 1; off < 16; off <<= 1)
      for (int r = 0; r < 4; ++r)
        pmax[r] = fmaxf(pmax[r], __shfl_xor(pmax[r], off, 64));
    float corr[4];
    #pragma unroll
    for (int r = 0; r < 4; ++r) {
      float mnew = fmaxf(m_run[r], pmax[r]);
      corr[r] = __expf(m_run[r] - mnew);
      m_run[r] = mnew;
      psum[r] = 0.0f;
    }
    #pragma unroll
    for (int cf = 0; cf < 4; ++cf) {
      const int col = cf * 16 + ln;
      #pragma unroll
      for (int r = 0; r < 4; ++r) {
        const int row = 4 * lg + r;
        float p = __expf(s[cf][r] * scale - m_run[r]);
        psum[r] += p;
        P_s[wid][row][col ^ ((row & 7) * 8)] = f2bf(p);
      }
    }
    #pragma unroll
    for (int off = 1; off < 16; off <<= 1)
      for (int r = 0; r < 4; ++r)
        psum[r] += __shfl_xor(psum[r], off, 64);
    #pragma unroll
    for (int r = 0; r < 4; ++r) l_run[r] = l_run[r] * corr[r] + psum[r];
    #pragma unroll
    for (int df = 0; df < 4; ++df)
      for (int r = 0; r < 4; ++r) oacc[df][r] *= corr[r];

    // ---- O += P @ V  (P_s is per-wave: wave-internal LDS order suffices) ----
    #pragma unroll
    for (int kc = 0; kc < 2; ++kc) {
      const int kk = kc * 32 + lg * 8;
      bf16x8 ap = *(const bf16x8*)&P_s[wid][ln][kk ^ ((ln & 7) * 8)];
      #pragma unroll
      for (int df = 0; df < 4; ++df) {
        const int n = df * 16 + ln;
        bf16x8 bv = *(const bf16x8*)&Vt_s[n][kk ^ ((n & 7) * 8)];
        oacc[df] = __builtin_amdgcn_mfma_f32_16x16x32_bf16(ap, bv, oacc[df], 0, 0, 0);
      }
    }
  }

  for (int r = 0; r < 4; ++r) l_run[r] = 1.0f / l_run[r];
  for (int df = 0; df < 4; ++df)
    for (int r = 0; r < 4; ++r) {
      const int row = r0 + 4 * lg + r;
      const int col = df * 16 + ln;
      O[(size_t)row * 64 + col] = f2bf(oacc[df][r] * l_run[r]);
    }
}

// ---------------------------------------------------------------------------
extern "C" void kernel_launch(void* const* d_in, const int* in_sizes, int n_in,
                              void* d_out, int out_size, void* d_ws, size_t ws_size,
                              hipStream_t stream) {
  const float* x    = (const float*)d_in[0];
  const float* xk   = (const float*)d_in[1];
  const float* Wv   = (const float*)d_in[2];  const float* bv   = (const float*)d_in[3];
  const float* Wk   = (const float*)d_in[4];  const float* bk   = (const float*)d_in[5];
  const float* Wq   = (const float*)d_in[6];  const float* bq   = (const float*)d_in[7];
  const float* Wkf  = (const float*)d_in[8];  const float* bkf  = (const float*)d_in[9];
  const float* Wqf  = (const float*)d_in[10]; const float* bqf  = (const float*)d_in[11];
  const float* Wq2  = (const float*)d_in[12]; const float* bq2  = (const float*)d_in[13];
  const float* Wk2  = (const float*)d_in[14]; const float* bk2  = (const float*)d_in[15];
  const float* Wqf2 = (const float*)d_in[16]; const float* bqf2 = (const float*)d_in[17];
  const float* Wkf2 = (const float*)d_in[18]; const float* bkf2 = (const float*)d_in[19];
  const float* Wo   = (const float*)d_in[20]; const float* bo   = (const float*)d_in[21];

  u16* ws = (u16*)d_ws;
  const size_t WSZ = 262144, BUF = 2097152;
  u16* Wt = ws;                     // 10 transposed bf16 weights
  u16* v1  = Wt + 10 * WSZ;
  u16* q1  = v1  + BUF;
  u16* k1  = q1  + BUF;
  u16* qf1 = k1  + BUF;
  u16* kf1 = qf1 + BUF;
  u16* q2  = kf1 + BUF;
  u16* k2  = q2  + BUF;
  u16* qf2 = k2  + BUF;
  u16* kf2 = qf2 + BUF;
  u16* att = kf2 + BUF;

  // Wt slots: 0 Wv, 1 Wk, 2 Wq, 3 Wkf, 4 Wqf, 5 Wq2, 6 Wk2, 7 Wqf2, 8 Wkf2, 9 Wo
  TPtrs tp;
  tp.p[0] = Wv;  tp.p[1] = Wk;   tp.p[2] = Wq;   tp.p[3] = Wkf; tp.p[4] = Wqf;
  tp.p[5] = Wq2; tp.p[6] = Wk2;  tp.p[7] = Wqf2; tp.p[8] = Wkf2; tp.p[9] = Wo;
  transposeW<<<dim3(8, 8, 10), 256, 0, stream>>>(tp, Wt);

  const dim3 gg(8, 64);   // N/64 x M/64, M = 4096
  gemm_bt<float, u16><<<gg, 256, 0, stream>>>(x,  Wt + 0 * WSZ, bv,  v1);
  gemm_bt<float, u16><<<gg, 256, 0, stream>>>(x,  Wt + 1 * WSZ, bk,  k1);
  gemm_bt<float, u16><<<gg, 256, 0, stream>>>(x,  Wt + 2 * WSZ, bq,  q1);
  gemm_bt<float, u16><<<gg, 256, 0, stream>>>(xk, Wt + 3 * WSZ, bkf, kf1);
  gemm_bt<float, u16><<<gg, 256, 0, stream>>>(xk, Wt + 4 * WSZ, bqf, qf1);

  gemm_bt<u16, u16><<<gg, 256, 0, stream>>>(q1,  Wt + 5 * WSZ, bq2,  q2);
  gemm_bt<u16, u16><<<gg, 256, 0, stream>>>(k1,  Wt + 6 * WSZ, bk2,  k2);
  gemm_bt<u16, u16><<<gg, 256, 0, stream>>>(qf1, Wt + 7 * WSZ, bqf2, qf2);
  gemm_bt<u16, u16><<<gg, 256, 0, stream>>>(kf1, Wt + 8 * WSZ, bkf2, kf2);

  attn_kernel<<<dim3(32, 16), 256, 0, stream>>>(q2, k2, qf2, kf2, v1, att);

  gemm_bt<u16, float><<<gg, 256, 0, stream>>>(att, Wt + 9 * WSZ, bo, (float*)d_out);
}

// Round 2
// 144.868 us; speedup vs baseline: 1.5660x; 1.5660x over previous
//
#include <hip/hip_runtime.h>

typedef unsigned short u16;
typedef unsigned int   u32;
typedef __attribute__((ext_vector_type(8))) short bf16x8;
typedef __attribute__((ext_vector_type(4))) float f32x4;

#define SCALE 0.08838834764831845f   // 1/sqrt(2*64)

__device__ inline u16 f2bf(float f) {
  u32 u = __builtin_bit_cast(u32, f);
  u = (u + 0x7FFFu + ((u >> 16) & 1u)) >> 16;   // RNE
  return (u16)u;
}

// ---------------------------------------------------------------------------
// fp32 -> bf16 bulk convert (x and x_knowledge). grid (1024, 2), 8 elems/thr.
// ---------------------------------------------------------------------------
__global__ __launch_bounds__(256) void cvt_bf16(const float* __restrict__ a,
                                                const float* __restrict__ b,
                                                u16* __restrict__ oa,
                                                u16* __restrict__ ob) {
  const float* in = blockIdx.y ? b : a;
  u16* out = blockIdx.y ? ob : oa;
  const int i = (blockIdx.x * 256 + threadIdx.x) * 8;
  float4 f0 = *(const float4*)(in + i);
  float4 f1 = *(const float4*)(in + i + 4);
  alignas(16) u16 t[8] = {f2bf(f0.x), f2bf(f0.y), f2bf(f0.z), f2bf(f0.w),
                          f2bf(f1.x), f2bf(f1.y), f2bf(f1.z), f2bf(f1.w)};
  *(uint4*)(out + i) = *(const uint4*)t;
}

// ---------------------------------------------------------------------------
// Weight transpose Wt[z][n][k] = W[z][k][n] (fp32->bf16); slots 5,7 scaled.
// ---------------------------------------------------------------------------
struct TPtrs { const float* p[10]; };

__global__ __launch_bounds__(256) void transposeW(TPtrs ptrs, u16* __restrict__ out) {
  __shared__ u16 ts[64][65];
  const float sc = (blockIdx.z == 5 || blockIdx.z == 7) ? SCALE : 1.0f;
  const float* in = ptrs.p[blockIdx.z];
  u16* o = out + (size_t)blockIdx.z * 262144;
  const int t = threadIdx.x;
  const int k0 = blockIdx.y * 64, n0 = blockIdx.x * 64;
  for (int pp = 0; pp < 16; ++pp) {
    int id = t + 256 * pp; int r = id >> 6, c = id & 63;
    ts[r][c] = f2bf(in[(size_t)(k0 + r) * 512 + n0 + c] * sc);
  }
  __syncthreads();
  for (int pp = 0; pp < 16; ++pp) {
    int id = t + 256 * pp; int r = id >> 6, c = id & 63;
    o[(size_t)(n0 + r) * 512 + k0 + c] = ts[c][r];
  }
}

// ---------------------------------------------------------------------------
// Pack 10 biases contiguously (slot order = Wt order); slots 5,7 scaled.
// ---------------------------------------------------------------------------
struct BPtrs { const float* p[10]; };

__global__ __launch_bounds__(512) void biasPack(BPtrs bp, float* __restrict__ out) {
  const int z = blockIdx.x, n = threadIdx.x;
  const float sc = (z == 5 || z == 7) ? SCALE : 1.0f;
  out[z * 512 + n] = bp.p[z][n] * sc;
}

// ---------------------------------------------------------------------------
// Per-head V transpose: v1 (2048,64) -> vt (64,2048) per head. grid (32,16).
// ---------------------------------------------------------------------------
__global__ __launch_bounds__(256) void transposeV(const u16* __restrict__ v1,
                                                  u16* __restrict__ vt) {
  __shared__ u16 ts[64][65];
  const size_t base = (size_t)blockIdx.y * 131072;
  const u16* in = v1 + base;
  u16* out = vt + base;
  const int l0 = blockIdx.x * 64;
  const int t = threadIdx.x;
  const int r = t >> 3, c8 = (t & 7) * 8;
  for (int pp = 0; pp < 2; ++pp) {
    int rr = r + pp * 32;
    *(uint4*)&ts[rr][c8] = *(const uint4*)&in[(size_t)(l0 + rr) * 64 + c8];
  }
  __syncthreads();
  for (int pp = 0; pp < 2; ++pp) {
    int d = r + pp * 32;
    alignas(16) u16 tmp[8];
    #pragma unroll
    for (int i = 0; i < 8; ++i) tmp[i] = ts[c8 + i][d];
    *(uint4*)&out[(size_t)d * 2048 + l0 + c8] = *(const uint4*)tmp;
  }
}

// ---------------------------------------------------------------------------
// Batched/fused GEMM: C = A[Mx512] @ Wt_rows^T + bias. BK=64, 2-phase
// double-buffered LDS, reg-staged (T14), XOR-swizzled tiles (T2).
// grid (N_total/64, 64, nz). Wt rows contiguous across slots.
// ---------------------------------------------------------------------------
struct GemmBatch {
  const u16* A[4];
  void* out[4][3];    // per z, per 512-column group
  int wslot0;
};

template <typename TOUT>
__global__ __launch_bounds__(256) void gemm2(GemmBatch gb,
    const u16* __restrict__ Wt, const float* __restrict__ biasP) {
  const int z = blockIdx.z;
  const u16* A = gb.A[z];
  const int n0 = blockIdx.x * 64, m0 = blockIdx.y * 64;
  const size_t rowbase = (size_t)(gb.wslot0 + z) * 512 + n0;
  const u16* B = Wt + rowbase * 512;
  const float* bias = biasP + rowbase;
  TOUT* C = (TOUT*)gb.out[z][n0 >> 9];
  const int nc0 = n0 & 511;

  const int t = threadIdx.x, wid = t >> 6, lane = t & 63;
  const int lg = lane >> 4, ln = lane & 15;
  const int wr = wid >> 1, wc = wid & 1;

  __shared__ u16 As[2][64][64];
  __shared__ u16 Bs[2][64][64];

  const int srow = t >> 2, sj = t & 3;
  const int sw0 = ((sj    ) ^ (srow & 7)) * 8;
  const int sw1 = ((sj + 4) ^ (srow & 7)) * 8;
  const u16* Asrc = A + (size_t)(m0 + srow) * 512 + sj * 8;
  const u16* Bsrc = B + (size_t)srow * 512 + sj * 8;

  uint4 ra0 = *(const uint4*)(Asrc);
  uint4 ra1 = *(const uint4*)(Asrc + 32);
  uint4 rb0 = *(const uint4*)(Bsrc);
  uint4 rb1 = *(const uint4*)(Bsrc + 32);
  *(uint4*)&As[0][srow][sw0] = ra0;  *(uint4*)&As[0][srow][sw1] = ra1;
  *(uint4*)&Bs[0][srow][sw0] = rb0;  *(uint4*)&Bs[0][srow][sw1] = rb1;
  __syncthreads();

  f32x4 acc[2][2];
  #pragma unroll
  for (int i = 0; i < 2; ++i)
    for (int j = 0; j < 2; ++j)
      for (int r = 0; r < 4; ++r) acc[i][j][r] = 0.0f;

  int cur = 0;
  for (int kt = 0; kt < 8; ++kt) {
    if (kt < 7) {
      const int ko = (kt + 1) * 64;
      ra0 = *(const uint4*)(Asrc + ko);
      ra1 = *(const uint4*)(Asrc + ko + 32);
      rb0 = *(const uint4*)(Bsrc + ko);
      rb1 = *(const uint4*)(Bsrc + ko + 32);
    }
    #pragma unroll
    for (int ck = 0; ck < 2; ++ck) {
      bf16x8 af[2], bfr[2];
      #pragma unroll
      for (int mi = 0; mi < 2; ++mi) {
        const int r = wr * 32 + mi * 16 + ln;
        af[mi] = *(const bf16x8*)&As[cur][r][((ck * 4 + lg) ^ (r & 7)) * 8];
      }
      #pragma unroll
      for (int ni = 0; ni < 2; ++ni) {
        const int r = wc * 32 + ni * 16 + ln;
        bfr[ni] = *(const bf16x8*)&Bs[cur][r][((ck * 4 + lg) ^ (r & 7)) * 8];
      }
      #pragma unroll
      for (int mi = 0; mi < 2; ++mi)
        #pragma unroll
        for (int ni = 0; ni < 2; ++ni)
          acc[mi][ni] = __builtin_amdgcn_mfma_f32_16x16x32_bf16(
              af[mi], bfr[ni], acc[mi][ni], 0, 0, 0);
    }
    if (kt < 7) {
      *(uint4*)&As[cur ^ 1][srow][sw0] = ra0;  *(uint4*)&As[cur ^ 1][srow][sw1] = ra1;
      *(uint4*)&Bs[cur ^ 1][srow][sw0] = rb0;  *(uint4*)&Bs[cur ^ 1][srow][sw1] = rb1;
      __syncthreads();
      cur ^= 1;
    }
  }

  #pragma unroll
  for (int ni = 0; ni < 2; ++ni) {
    const int col = nc0 + wc * 32 + ni * 16 + ln;
    const float bv = bias[wc * 32 + ni * 16 + ln];
    #pragma unroll
    for (int mi = 0; mi < 2; ++mi)
      #pragma unroll
      for (int r = 0; r < 4; ++r) {
        const int row = m0 + wr * 32 + mi * 16 + 4 * lg + r;
        const float val = acc[mi][ni][r] + bv;
        if constexpr (sizeof(TOUT) == 4) C[(size_t)row * 512 + col] = val;
        else                             C[(size_t)row * 512 + col] = f2bf(val);
      }
  }
}

// ---------------------------------------------------------------------------
// Flash attention, 2-phase pipelined. Q pre-scaled (scale folded into GEMM).
// V pre-transposed (vt). Defer-max rescale (THR=8). grid (32,16), 4 waves.
// ---------------------------------------------------------------------------
__global__ __launch_bounds__(256) void attn2(
    const u16* __restrict__ q2, const u16* __restrict__ k2,
    const u16* __restrict__ qf2, const u16* __restrict__ kf2,
    const u16* __restrict__ vt, u16* __restrict__ att_out) {
  const size_t base = (size_t)blockIdx.y * 131072;
  const u16* Q  = q2  + base;
  const u16* K  = k2  + base;
  const u16* Qf = qf2 + base;
  const u16* Kf = kf2 + base;
  const u16* Vt = vt  + base;
  u16* O = att_out + base;

  const int t = threadIdx.x, wid = t >> 6, lane = t & 63;
  const int lg = lane >> 4, ln = lane & 15;
  const int r0 = blockIdx.x * 64 + wid * 16;

  __shared__ u16 K_s [2][64][64];
  __shared__ u16 Kf_s[2][64][64];
  __shared__ u16 Vt_s[2][64][64];
  __shared__ u16 P_s [4][16][64];

  const int srow = t >> 2, sj = t & 3;
  const int sw0 = ((sj    ) ^ (srow & 7)) * 8;
  const int sw1 = ((sj + 4) ^ (srow & 7)) * 8;
  const u16* Ksrc  = K  + (size_t)srow * 64 + sj * 8;
  const u16* Kfsrc = Kf + (size_t)srow * 64 + sj * 8;
  const u16* Vsrc  = Vt + (size_t)srow * 2048 + sj * 8;

  bf16x8 aq[4];
  {
    const int row = r0 + ln;
    aq[0] = *(const bf16x8*)&Q [row * 64 +      lg * 8];
    aq[1] = *(const bf16x8*)&Q [row * 64 + 32 + lg * 8];
    aq[2] = *(const bf16x8*)&Qf[row * 64 +      lg * 8];
    aq[3] = *(const bf16x8*)&Qf[row * 64 + 32 + lg * 8];
  }

  f32x4 oacc[4];
  #pragma unroll
  for (int i = 0; i < 4; ++i)
    for (int r = 0; r < 4; ++r) oacc[i][r] = 0.0f;
  float m_run[4], l_run[4];
  #pragma unroll
  for (int r = 0; r < 4; ++r) { m_run[r] = -1e30f; l_run[r] = 0.0f; }

  // prologue: stage tile 0
  uint4 rk0 = *(const uint4*)(Ksrc);
  uint4 rk1 = *(const uint4*)(Ksrc + 32);
  uint4 rf0 = *(const uint4*)(Kfsrc);
  uint4 rf1 = *(const uint4*)(Kfsrc + 32);
  uint4 rv0 = *(const uint4*)(Vsrc);
  uint4 rv1 = *(const uint4*)(Vsrc + 32);
  *(uint4*)&K_s [0][srow][sw0] = rk0;  *(uint4*)&K_s [0][srow][sw1] = rk1;
  *(uint4*)&Kf_s[0][srow][sw0] = rf0;  *(uint4*)&Kf_s[0][srow][sw1] = rf1;
  *(uint4*)&Vt_s[0][srow][sw0] = rv0;  *(uint4*)&Vt_s[0][srow][sw1] = rv1;
  __syncthreads();

  int cur = 0;
  for (int kt = 0; kt < 32; ++kt) {
    if (kt < 31) {
      const int ko = (kt + 1) * 64;
      rk0 = *(const uint4*)(Ksrc  + (size_t)ko * 64);
      rk1 = *(const uint4*)(Ksrc  + (size_t)ko * 64 + 32);
      rf0 = *(const uint4*)(Kfsrc + (size_t)ko * 64);
      rf1 = *(const uint4*)(Kfsrc + (size_t)ko * 64 + 32);
      rv0 = *(const uint4*)(Vsrc  + ko);
      rv1 = *(const uint4*)(Vsrc  + ko + 32);
    }

    // ---- S = Q K^T + Qf Kf^T (already scaled) ----
    f32x4 s[4];
    #pragma unroll
    for (int cf = 0; cf < 4; ++cf) {
      f32x4 a;
      #pragma unroll
      for (int r = 0; r < 4; ++r) a[r] = 0.0f;
      const int n = cf * 16 + ln;
      const int sx = n & 7;
      bf16x8 b0 = *(const bf16x8*)&K_s [cur][n][((0 + lg) ^ sx) * 8];
      a = __builtin_amdgcn_mfma_f32_16x16x32_bf16(aq[0], b0, a, 0, 0, 0);
      bf16x8 b1 = *(const bf16x8*)&K_s [cur][n][((4 + lg) ^ sx) * 8];
      a = __builtin_amdgcn_mfma_f32_16x16x32_bf16(aq[1], b1, a, 0, 0, 0);
      bf16x8 b2 = *(const bf16x8*)&Kf_s[cur][n][((0 + lg) ^ sx) * 8];
      a = __builtin_amdgcn_mfma_f32_16x16x32_bf16(aq[2], b2, a, 0, 0, 0);
      bf16x8 b3 = *(const bf16x8*)&Kf_s[cur][n][((4 + lg) ^ sx) * 8];
      a = __builtin_amdgcn_mfma_f32_16x16x32_bf16(aq[3], b3, a, 0, 0, 0);
      s[cf] = a;
    }

    // ---- online softmax with defer-max ----
    float pmax[4], psum[4];
    #pragma unroll
    for (int r = 0; r < 4; ++r)
      pmax[r] = fmaxf(fmaxf(s[0][r], s[1][r]), fmaxf(s[2][r], s[3][r]));
    #pragma unroll
    for (int off = 1; off < 16; off <<= 1)
      #pragma unroll
      for (int r = 0; r < 4; ++r)
        pmax[r] = fmaxf(pmax[r], __shfl_xor(pmax[r], off, 64));
    const float dmax = fmaxf(fmaxf(pmax[0] - m_run[0], pmax[1] - m_run[1]),
                             fmaxf(pmax[2] - m_run[2], pmax[3] - m_run[3]));
    if (__any(dmax > 8.0f)) {
      #pragma unroll
      for (int r = 0; r < 4; ++r) {
        const float mnew = fmaxf(m_run[r], pmax[r]);
        const float corr = __expf(m_run[r] - mnew);
        m_run[r] = mnew;
        l_run[r] *= corr;
        #pragma unroll
        for (int df = 0; df < 4; ++df) oacc[df][r] *= corr;
      }
    }
    #pragma unroll
    for (int r = 0; r < 4; ++r) psum[r] = 0.0f;
    #pragma unroll
    for (int cf = 0; cf < 4; ++cf) {
      const int col = cf * 16 + ln;
      #pragma unroll
      for (int r = 0; r < 4; ++r) {
        const int row = 4 * lg + r;
        const float p = __expf(s[cf][r] - m_run[r]);
        psum[r] += p;
        P_s[wid][row][col ^ ((row & 7) * 8)] = f2bf(p);
      }
    }
    #pragma unroll
    for (int off = 1; off < 16; off <<= 1)
      #pragma unroll
      for (int r = 0; r < 4; ++r)
        psum[r] += __shfl_xor(psum[r], off, 64);
    #pragma unroll
    for (int r = 0; r < 4; ++r) l_run[r] += psum[r];

    // ---- O += P @ V ----
    #pragma unroll
    for (int kc = 0; kc < 2; ++kc) {
      const int kk = kc * 32 + lg * 8;
      bf16x8 ap = *(const bf16x8*)&P_s[wid][ln][kk ^ ((ln & 7) * 8)];
      #pragma unroll
      for (int df = 0; df < 4; ++df) {
        const int n = df * 16 + ln;
        bf16x8 bv = *(const bf16x8*)&Vt_s[cur][n][((kc * 4 + lg) ^ (n & 7)) * 8];
        oacc[df] = __builtin_amdgcn_mfma_f32_16x16x32_bf16(ap, bv, oacc[df], 0, 0, 0);
      }
    }

    if (kt < 31) {
      *(uint4*)&K_s [cur ^ 1][srow][sw0] = rk0;  *(uint4*)&K_s [cur ^ 1][srow][sw1] = rk1;
      *(uint4*)&Kf_s[cur ^ 1][srow][sw0] = rf0;  *(uint4*)&Kf_s[cur ^ 1][srow][sw1] = rf1;
      *(uint4*)&Vt_s[cur ^ 1][srow][sw0] = rv0;  *(uint4*)&Vt_s[cur ^ 1][srow][sw1] = rv1;
      __syncthreads();
      cur ^= 1;
    }
  }

  #pragma unroll
  for (int r = 0; r < 4; ++r) l_run[r] = 1.0f / l_run[r];
  #pragma unroll
  for (int df = 0; df < 4; ++df)
    #pragma unroll
    for (int r = 0; r < 4; ++r) {
      const int row = r0 + 4 * lg + r;
      const int col = df * 16 + ln;
      O[(size_t)row * 64 + col] = f2bf(oacc[df][r] * l_run[r]);
    }
}

// ---------------------------------------------------------------------------
extern "C" void kernel_launch(void* const* d_in, const int* in_sizes, int n_in,
                              void* d_out, int out_size, void* d_ws, size_t ws_size,
                              hipStream_t stream) {
  const float* x    = (const float*)d_in[0];
  const float* xk   = (const float*)d_in[1];
  const float* Wv   = (const float*)d_in[2];  const float* bv   = (const float*)d_in[3];
  const float* Wk   = (const float*)d_in[4];  const float* bk   = (const float*)d_in[5];
  const float* Wq   = (const float*)d_in[6];  const float* bq   = (const float*)d_in[7];
  const float* Wkf  = (const float*)d_in[8];  const float* bkf  = (const float*)d_in[9];
  const float* Wqf  = (const float*)d_in[10]; const float* bqf  = (const float*)d_in[11];
  const float* Wq2  = (const float*)d_in[12]; const float* bq2  = (const float*)d_in[13];
  const float* Wk2  = (const float*)d_in[14]; const float* bk2  = (const float*)d_in[15];
  const float* Wqf2 = (const float*)d_in[16]; const float* bqf2 = (const float*)d_in[17];
  const float* Wkf2 = (const float*)d_in[18]; const float* bkf2 = (const float*)d_in[19];
  const float* Wo   = (const float*)d_in[20]; const float* bo   = (const float*)d_in[21];

  u16* ws = (u16*)d_ws;
  u16* Wt = ws;                                   // 10 x 262144 u16
  float* biasP = (float*)(ws + 2621440);          // 5120 f32
  u16* bufs = ws + 2621440 + 10240;
  const size_t BUF = 2097152;
  u16* v1  = bufs + 0 * BUF;
  u16* k1  = bufs + 1 * BUF;
  u16* q1  = bufs + 2 * BUF;   // later reused as vt
  u16* kf1 = bufs + 3 * BUF;   // later reused as att
  u16* qf1 = bufs + 4 * BUF;
  u16* q2  = bufs + 5 * BUF;   // first used as xb
  u16* k2  = bufs + 6 * BUF;   // first used as xkb
  u16* qf2 = bufs + 7 * BUF;
  u16* kf2 = bufs + 8 * BUF;

  // 1. x, xk -> bf16 (into q2/k2 slots, dead until stage-2 writes them)
  cvt_bf16<<<dim3(1024, 2), 256, 0, stream>>>(x, xk, q2, k2);

  // 2. weights -> bf16 transposed (scale folded into slots 5,7)
  TPtrs tp;
  tp.p[0] = Wv;  tp.p[1] = Wk;  tp.p[2] = Wq;   tp.p[3] = Wkf;  tp.p[4] = Wqf;
  tp.p[5] = Wq2; tp.p[6] = Wk2; tp.p[7] = Wqf2; tp.p[8] = Wkf2; tp.p[9] = Wo;
  transposeW<<<dim3(8, 8, 10), 256, 0, stream>>>(tp, Wt);

  // 3. biases packed (scale folded into slots 5,7)
  BPtrs bp;
  bp.p[0] = bv;  bp.p[1] = bk;  bp.p[2] = bq;   bp.p[3] = bkf;  bp.p[4] = bqf;
  bp.p[5] = bq2; bp.p[6] = bk2; bp.p[7] = bqf2; bp.p[8] = bkf2; bp.p[9] = bo;
  biasPack<<<dim3(10), 512, 0, stream>>>(bp, biasP);

  // 4. stage-1 fused: x @ [Wv|Wk|Wq] -> v1,k1,q1
  GemmBatch g1 = {};
  g1.A[0] = q2;  g1.wslot0 = 0;
  g1.out[0][0] = v1; g1.out[0][1] = k1; g1.out[0][2] = q1;
  gemm2<u16><<<dim3(24, 64, 1), 256, 0, stream>>>(g1, Wt, biasP);

  // 5. stage-1 fused: xk @ [Wkf|Wqf] -> kf1,qf1
  GemmBatch g2 = {};
  g2.A[0] = k2;  g2.wslot0 = 3;
  g2.out[0][0] = kf1; g2.out[0][1] = qf1;
  gemm2<u16><<<dim3(16, 64, 1), 256, 0, stream>>>(g2, Wt, biasP);

  // 6. stage-2 batched: {q1,k1,qf1,kf1} @ {Wq2,Wk2,Wqf2,Wkf2} -> {q2,k2,qf2,kf2}
  GemmBatch g3 = {};
  g3.A[0] = q1; g3.A[1] = k1; g3.A[2] = qf1; g3.A[3] = kf1;
  g3.wslot0 = 5;
  g3.out[0][0] = q2; g3.out[1][0] = k2; g3.out[2][0] = qf2; g3.out[3][0] = kf2;
  gemm2<u16><<<dim3(8, 64, 4), 256, 0, stream>>>(g3, Wt, biasP);

  // 7. V transpose per head (into q1 slot, dead after stage-2)
  transposeV<<<dim3(32, 16), 256, 0, stream>>>(v1, q1);

  // 8. attention (att into kf1 slot, dead after stage-2)
  attn2<<<dim3(32, 16), 256, 0, stream>>>(q2, k2, qf2, kf2, q1, kf1);

  // 9. final: att @ Wo + bo -> d_out (fp32)
  GemmBatch g4 = {};
  g4.A[0] = kf1; g4.wslot0 = 9;
  g4.out[0][0] = d_out;
  gemm2<float><<<dim3(8, 64, 1), 256, 0, stream>>>(g4, Wt, biasP);
}

// Round 3
// 138.857 us; speedup vs baseline: 1.6338x; 1.0433x over previous
//
#include <hip/hip_runtime.h>

typedef unsigned short u16;
typedef unsigned int   u32;
typedef __attribute__((ext_vector_type(8))) short bf16x8;
typedef __attribute__((ext_vector_type(4))) float f32x4;

#define SCALE 0.08838834764831845f                 // 1/sqrt(2*64)
#define SCLOG 0.12752040542575836f                 // SCALE * log2(e)

__device__ inline u16 f2bf(float f) {
  u32 u = __builtin_bit_cast(u32, f);
  u = (u + 0x7FFFu + ((u >> 16) & 1u)) >> 16;      // RNE
  return (u16)u;
}

// ---------------------------------------------------------------------------
// fp32 -> bf16 bulk convert (x and x_knowledge). grid (1024, 2), 8 elems/thr.
// ---------------------------------------------------------------------------
__global__ __launch_bounds__(256) void cvt_bf16(const float* __restrict__ a,
                                                const float* __restrict__ b,
                                                u16* __restrict__ oa,
                                                u16* __restrict__ ob) {
  const float* in = blockIdx.y ? b : a;
  u16* out = blockIdx.y ? ob : oa;
  const int i = (blockIdx.x * 256 + threadIdx.x) * 8;
  float4 f0 = *(const float4*)(in + i);
  float4 f1 = *(const float4*)(in + i + 4);
  alignas(16) u16 t[8] = {f2bf(f0.x), f2bf(f0.y), f2bf(f0.z), f2bf(f0.w),
                          f2bf(f1.x), f2bf(f1.y), f2bf(f1.z), f2bf(f1.w)};
  *(uint4*)(out + i) = *(const uint4*)t;
}

// ---------------------------------------------------------------------------
// Weight transpose Wt[z][n][k] = W[z][k][n] (fp32->bf16); slots 5,7 scaled
// by SCALE*log2e (folds both attn scale and exp->exp2 conversion into Q,Qf).
// ---------------------------------------------------------------------------
struct TPtrs { const float* p[10]; };

__global__ __launch_bounds__(256) void transposeW(TPtrs ptrs, u16* __restrict__ out) {
  __shared__ u16 ts[64][65];
  const float sc = (blockIdx.z == 5 || blockIdx.z == 7) ? SCLOG : 1.0f;
  const float* in = ptrs.p[blockIdx.z];
  u16* o = out + (size_t)blockIdx.z * 262144;
  const int t = threadIdx.x;
  const int k0 = blockIdx.y * 64, n0 = blockIdx.x * 64;
  for (int pp = 0; pp < 16; ++pp) {
    int id = t + 256 * pp; int r = id >> 6, c = id & 63;
    ts[r][c] = f2bf(in[(size_t)(k0 + r) * 512 + n0 + c] * sc);
  }
  __syncthreads();
  for (int pp = 0; pp < 16; ++pp) {
    int id = t + 256 * pp; int r = id >> 6, c = id & 63;
    o[(size_t)(n0 + r) * 512 + k0 + c] = ts[c][r];
  }
}

struct BPtrs { const float* p[10]; };

__global__ __launch_bounds__(512) void biasPack(BPtrs bp, float* __restrict__ out) {
  const int z = blockIdx.x, n = threadIdx.x;
  const float sc = (z == 5 || z == 7) ? SCLOG : 1.0f;
  out[z * 512 + n] = bp.p[z][n] * sc;
}

// ---------------------------------------------------------------------------
// Per-head V transpose: v1 (2048,64) -> vt (64,2048) per head. grid (32,16).
// ---------------------------------------------------------------------------
__global__ __launch_bounds__(256) void transposeV(const u16* __restrict__ v1,
                                                  u16* __restrict__ vt) {
  __shared__ u16 ts[64][65];
  const size_t base = (size_t)blockIdx.y * 131072;
  const u16* in = v1 + base;
  u16* out = vt + base;
  const int l0 = blockIdx.x * 64;
  const int t = threadIdx.x;
  const int r = t >> 3, c8 = (t & 7) * 8;
  for (int pp = 0; pp < 2; ++pp) {
    int rr = r + pp * 32;
    *(uint4*)&ts[rr][c8] = *(const uint4*)&in[(size_t)(l0 + rr) * 64 + c8];
  }
  __syncthreads();
  for (int pp = 0; pp < 2; ++pp) {
    int d = r + pp * 32;
    alignas(16) u16 tmp[8];
    #pragma unroll
    for (int i = 0; i < 8; ++i) tmp[i] = ts[c8 + i][d];
    *(uint4*)&out[(size_t)d * 2048 + l0 + c8] = *(const uint4*)tmp;
  }
}

// ---------------------------------------------------------------------------
// GEMM: 128x128 tile, BK=64, 4 waves (2x2) of 64x64 each. 2-phase dbuf,
// reg-staged, XOR-swizzled LDS. Wt treated as one (5120 x 512) matrix.
// grid (Ntot/128, 32, nz).
// ---------------------------------------------------------------------------
struct GemmBatch {
  const u16* A[4];
  void* out[4][3];     // per z, per 512-column group
  int wrow0;           // start row in 5120x512 Wt
  int zstride;         // row stride per z
};

template <typename TOUT>
__global__ __launch_bounds__(256, 2) void gemm3(GemmBatch gb,
    const u16* __restrict__ Wt, const float* __restrict__ biasP) {
  const int z = blockIdx.z;
  const u16* A = gb.A[z];
  const int n0 = blockIdx.x * 128, m0 = blockIdx.y * 128;
  const int wrow = gb.wrow0 + z * gb.zstride + n0;
  const u16* B = Wt + (size_t)wrow * 512;
  const float* bias = biasP + wrow;
  TOUT* C = (TOUT*)gb.out[z][n0 >> 9];
  const int nc0 = n0 & 511;

  const int t = threadIdx.x, wid = t >> 6, lane = t & 63;
  const int lg = lane >> 4, ln = lane & 15;
  const int wr = wid >> 1, wc = wid & 1;

  __shared__ u16 As[2][128][64];
  __shared__ u16 Bs[2][128][64];

  const int srow = t >> 3, sch = t & 7;        // 32 rows x 8 chunks, x4 passes
  const int sw = (sch ^ (srow & 7)) * 8;       // (srow+32p)&7 == srow&7
  const u16* Asrc = A + (size_t)(m0 + srow) * 512 + sch * 8;
  const u16* Bsrc = B + (size_t)srow * 512 + sch * 8;

  uint4 ra[4], rb[4];
  #pragma unroll
  for (int p = 0; p < 4; ++p) {
    ra[p] = *(const uint4*)(Asrc + p * 32 * 512);
    rb[p] = *(const uint4*)(Bsrc + p * 32 * 512);
  }
  #pragma unroll
  for (int p = 0; p < 4; ++p) {
    *(uint4*)&As[0][srow + 32 * p][sw] = ra[p];
    *(uint4*)&Bs[0][srow + 32 * p][sw] = rb[p];
  }
  __syncthreads();

  f32x4 acc[4][4];
  #pragma unroll
  for (int i = 0; i < 4; ++i)
    #pragma unroll
    for (int j = 0; j < 4; ++j)
      #pragma unroll
      for (int r = 0; r < 4; ++r) acc[i][j][r] = 0.0f;

  int cur = 0;
  for (int kt = 0; kt < 8; ++kt) {
    if (kt < 7) {
      const int ko = (kt + 1) * 64;
      #pragma unroll
      for (int p = 0; p < 4; ++p) {
        ra[p] = *(const uint4*)(Asrc + ko + p * 32 * 512);
        rb[p] = *(const uint4*)(Bsrc + ko + p * 32 * 512);
      }
    }
    #pragma unroll
    for (int ck = 0; ck < 2; ++ck) {
      bf16x8 af[4], bfr[4];
      #pragma unroll
      for (int mi = 0; mi < 4; ++mi) {
        const int r = wr * 64 + mi * 16 + ln;
        af[mi] = *(const bf16x8*)&As[cur][r][((ck * 4 + lg) ^ (r & 7)) * 8];
      }
      #pragma unroll
      for (int ni = 0; ni < 4; ++ni) {
        const int r = wc * 64 + ni * 16 + ln;
        bfr[ni] = *(const bf16x8*)&Bs[cur][r][((ck * 4 + lg) ^ (r & 7)) * 8];
      }
      #pragma unroll
      for (int mi = 0; mi < 4; ++mi)
        #pragma unroll
        for (int ni = 0; ni < 4; ++ni)
          acc[mi][ni] = __builtin_amdgcn_mfma_f32_16x16x32_bf16(
              af[mi], bfr[ni], acc[mi][ni], 0, 0, 0);
    }
    if (kt < 7) {
      #pragma unroll
      for (int p = 0; p < 4; ++p) {
        *(uint4*)&As[cur ^ 1][srow + 32 * p][sw] = ra[p];
        *(uint4*)&Bs[cur ^ 1][srow + 32 * p][sw] = rb[p];
      }
      __syncthreads();
      cur ^= 1;
    }
  }

  #pragma unroll
  for (int ni = 0; ni < 4; ++ni) {
    const int colw = wc * 64 + ni * 16 + ln;
    const float bv = bias[colw];
    const int col = nc0 + colw;
    #pragma unroll
    for (int mi = 0; mi < 4; ++mi)
      #pragma unroll
      for (int r = 0; r < 4; ++r) {
        const int row = m0 + wr * 64 + mi * 16 + 4 * lg + r;
        const float val = acc[mi][ni][r] + bv;
        if constexpr (sizeof(TOUT) == 4) C[(size_t)row * 512 + col] = val;
        else                             C[(size_t)row * 512 + col] = f2bf(val);
      }
  }
}

// ---------------------------------------------------------------------------
// Flash attention: QBLK=128 (4 waves x 32 rows), KVBLK=64, 2-phase dbuf.
// Q pre-scaled by SCALE*log2e -> P = exp2(s - m). Lane-local defer-max
// (THR=11 in log2 domain); l reduced once in epilogue. grid (256) linear,
// XCD-bijective swizzle.
// ---------------------------------------------------------------------------
__global__ __launch_bounds__(256) void attn3(
    const u16* __restrict__ q2, const u16* __restrict__ k2,
    const u16* __restrict__ qf2, const u16* __restrict__ kf2,
    const u16* __restrict__ vtg, u16* __restrict__ att_out) {
  const int id = blockIdx.x;
  const int nid = (id & 7) * 32 + (id >> 3);   // XCD gets 2 whole heads
  const int qt = nid & 15, bh = nid >> 4;
  const size_t base = (size_t)bh * 131072;
  const u16* Q  = q2  + base;
  const u16* K  = k2  + base;
  const u16* Qf = qf2 + base;
  const u16* Kf = kf2 + base;
  const u16* Vt = vtg + base;
  u16* O = att_out + base;

  const int t = threadIdx.x, wid = t >> 6, lane = t & 63;
  const int lg = lane >> 4, ln = lane & 15;
  const int r0 = qt * 128 + wid * 32;          // this wave's 32 Q rows

  __shared__ u16 K_s [2][64][64];
  __shared__ u16 Kf_s[2][64][64];
  __shared__ u16 Vt_s[2][64][64];
  __shared__ u16 P_s [4][32][64];

  const int srow = t >> 3, sch = t & 7;
  const int sw = (sch ^ (srow & 7)) * 8;
  const u16* Ksrc  = K  + (size_t)srow * 64 + sch * 8;
  const u16* Kfsrc = Kf + (size_t)srow * 64 + sch * 8;
  const u16* Vsrc  = Vt + (size_t)srow * 2048 + sch * 8;

  bf16x8 aq[2][4];
  #pragma unroll
  for (int mi = 0; mi < 2; ++mi) {
    const int row = r0 + mi * 16 + ln;
    aq[mi][0] = *(const bf16x8*)&Q [row * 64 +      lg * 8];
    aq[mi][1] = *(const bf16x8*)&Q [row * 64 + 32 + lg * 8];
    aq[mi][2] = *(const bf16x8*)&Qf[row * 64 +      lg * 8];
    aq[mi][3] = *(const bf16x8*)&Qf[row * 64 + 32 + lg * 8];
  }

  f32x4 oacc[2][4];
  #pragma unroll
  for (int mi = 0; mi < 2; ++mi)
    #pragma unroll
    for (int df = 0; df < 4; ++df)
      #pragma unroll
      for (int r = 0; r < 4; ++r) oacc[mi][df][r] = 0.0f;
  float m_run[2][4], l_par[2][4];
  #pragma unroll
  for (int mi = 0; mi < 2; ++mi)
    #pragma unroll
    for (int r = 0; r < 4; ++r) { m_run[mi][r] = -1e30f; l_par[mi][r] = 0.0f; }

  // prologue: stage tile 0
  uint4 rk0 = *(const uint4*)(Ksrc);
  uint4 rk1 = *(const uint4*)(Ksrc + 2048);
  uint4 rf0 = *(const uint4*)(Kfsrc);
  uint4 rf1 = *(const uint4*)(Kfsrc + 2048);
  uint4 rv0 = *(const uint4*)(Vsrc);
  uint4 rv1 = *(const uint4*)(Vsrc + 65536);
  *(uint4*)&K_s [0][srow][sw] = rk0;  *(uint4*)&K_s [0][srow + 32][sw] = rk1;
  *(uint4*)&Kf_s[0][srow][sw] = rf0;  *(uint4*)&Kf_s[0][srow + 32][sw] = rf1;
  *(uint4*)&Vt_s[0][srow][sw] = rv0;  *(uint4*)&Vt_s[0][srow + 32][sw] = rv1;
  __syncthreads();

  int cur = 0;
  for (int kt = 0; kt < 32; ++kt) {
    if (kt < 31) {
      const int ko = (kt + 1) * 4096;
      rk0 = *(const uint4*)(Ksrc  + ko);
      rk1 = *(const uint4*)(Ksrc  + ko + 2048);
      rf0 = *(const uint4*)(Kfsrc + ko);
      rf1 = *(const uint4*)(Kfsrc + ko + 2048);
      rv0 = *(const uint4*)(Vsrc  + (kt + 1) * 64);
      rv1 = *(const uint4*)(Vsrc  + (kt + 1) * 64 + 65536);
    }

    // ---- S = Q K^T + Qf Kf^T (pre-scaled, log2 domain) ----
    f32x4 s[2][4];
    #pragma unroll
    for (int cf = 0; cf < 4; ++cf) {
      const int n = cf * 16 + ln;
      const int sx = n & 7;
      bf16x8 b0 = *(const bf16x8*)&K_s [cur][n][((0 + lg) ^ sx) * 8];
      bf16x8 b1 = *(const bf16x8*)&K_s [cur][n][((4 + lg) ^ sx) * 8];
      bf16x8 b2 = *(const bf16x8*)&Kf_s[cur][n][((0 + lg) ^ sx) * 8];
      bf16x8 b3 = *(const bf16x8*)&Kf_s[cur][n][((4 + lg) ^ sx) * 8];
      #pragma unroll
      for (int mi = 0; mi < 2; ++mi) {
        f32x4 a;
        #pragma unroll
        for (int r = 0; r < 4; ++r) a[r] = 0.0f;
        a = __builtin_amdgcn_mfma_f32_16x16x32_bf16(aq[mi][0], b0, a, 0, 0, 0);
        a = __builtin_amdgcn_mfma_f32_16x16x32_bf16(aq[mi][1], b1, a, 0, 0, 0);
        a = __builtin_amdgcn_mfma_f32_16x16x32_bf16(aq[mi][2], b2, a, 0, 0, 0);
        a = __builtin_amdgcn_mfma_f32_16x16x32_bf16(aq[mi][3], b3, a, 0, 0, 0);
        s[mi][cf] = a;
      }
    }

    // ---- defer-max online softmax (lane-local trigger check) ----
    float smax[2][4];
    bool viol = false;
    #pragma unroll
    for (int mi = 0; mi < 2; ++mi)
      #pragma unroll
      for (int r = 0; r < 4; ++r) {
        smax[mi][r] = fmaxf(fmaxf(s[mi][0][r], s[mi][1][r]),
                            fmaxf(s[mi][2][r], s[mi][3][r]));
        viol = viol || (smax[mi][r] > m_run[mi][r] + 11.0f);
      }
    if (__any(viol)) {
      #pragma unroll
      for (int off = 1; off < 16; off <<= 1)
        #pragma unroll
        for (int mi = 0; mi < 2; ++mi)
          #pragma unroll
          for (int r = 0; r < 4; ++r)
            smax[mi][r] = fmaxf(smax[mi][r], __shfl_xor(smax[mi][r], off, 64));
      #pragma unroll
      for (int mi = 0; mi < 2; ++mi)
        #pragma unroll
        for (int r = 0; r < 4; ++r) {
          const float mnew = fmaxf(m_run[mi][r], smax[mi][r]);
          const float corr = exp2f(m_run[mi][r] - mnew);
          m_run[mi][r] = mnew;
          l_par[mi][r] *= corr;
          #pragma unroll
          for (int df = 0; df < 4; ++df) oacc[mi][df][r] *= corr;
        }
    }
    #pragma unroll
    for (int mi = 0; mi < 2; ++mi)
      #pragma unroll
      for (int cf = 0; cf < 4; ++cf) {
        const int col = cf * 16 + ln;
        #pragma unroll
        for (int r = 0; r < 4; ++r) {
          const int rr = 4 * lg + r;
          const float p = exp2f(s[mi][cf][r] - m_run[mi][r]);
          l_par[mi][r] += p;
          P_s[wid][mi * 16 + rr][col ^ ((rr & 7) * 8)] = f2bf(p);
        }
      }

    // ---- O += P @ V ----
    #pragma unroll
    for (int kc = 0; kc < 2; ++kc) {
      const int kk = kc * 32 + lg * 8;
      bf16x8 ap0 = *(const bf16x8*)&P_s[wid][ln]     [kk ^ ((ln & 7) * 8)];
      bf16x8 ap1 = *(const bf16x8*)&P_s[wid][16 + ln][kk ^ ((ln & 7) * 8)];
      #pragma unroll
      for (int df = 0; df < 4; ++df) {
        const int n = df * 16 + ln;
        bf16x8 bv = *(const bf16x8*)&Vt_s[cur][n][((kc * 4 + lg) ^ (n & 7)) * 8];
        oacc[0][df] = __builtin_amdgcn_mfma_f32_16x16x32_bf16(ap0, bv, oacc[0][df], 0, 0, 0);
        oacc[1][df] = __builtin_amdgcn_mfma_f32_16x16x32_bf16(ap1, bv, oacc[1][df], 0, 0, 0);
      }
    }

    if (kt < 31) {
      *(uint4*)&K_s [cur ^ 1][srow][sw] = rk0;  *(uint4*)&K_s [cur ^ 1][srow + 32][sw] = rk1;
      *(uint4*)&Kf_s[cur ^ 1][srow][sw] = rf0;  *(uint4*)&Kf_s[cur ^ 1][srow + 32][sw] = rf1;
      *(uint4*)&Vt_s[cur ^ 1][srow][sw] = rv0;  *(uint4*)&Vt_s[cur ^ 1][srow + 32][sw] = rv1;
      __syncthreads();
      cur ^= 1;
    }
  }

  // epilogue: reduce l across the 16 lanes of each row group, normalize, store
  #pragma unroll
  for (int off = 1; off < 16; off <<= 1)
    #pragma unroll
    for (int mi = 0; mi < 2; ++mi)
      #pragma unroll
      for (int r = 0; r < 4; ++r)
        l_par[mi][r] += __shfl_xor(l_par[mi][r], off, 64);
  #pragma unroll
  for (int mi = 0; mi < 2; ++mi)
    #pragma unroll
    for (int r = 0; r < 4; ++r) l_par[mi][r] = 1.0f / l_par[mi][r];

  #pragma unroll
  for (int mi = 0; mi < 2; ++mi)
    #pragma unroll
    for (int df = 0; df < 4; ++df)
      #pragma unroll
      for (int r = 0; r < 4; ++r) {
        const int row = r0 + mi * 16 + 4 * lg + r;
        const int col = df * 16 + ln;
        O[(size_t)row * 64 + col] = f2bf(oacc[mi][df][r] * l_par[mi][r]);
      }
}

// ---------------------------------------------------------------------------
extern "C" void kernel_launch(void* const* d_in, const int* in_sizes, int n_in,
                              void* d_out, int out_size, void* d_ws, size_t ws_size,
                              hipStream_t stream) {
  const float* x    = (const float*)d_in[0];
  const float* xk   = (const float*)d_in[1];
  const float* Wv   = (const float*)d_in[2];  const float* bv   = (const float*)d_in[3];
  const float* Wk   = (const float*)d_in[4];  const float* bk   = (const float*)d_in[5];
  const float* Wq   = (const float*)d_in[6];  const float* bq   = (const float*)d_in[7];
  const float* Wkf  = (const float*)d_in[8];  const float* bkf  = (const float*)d_in[9];
  const float* Wqf  = (const float*)d_in[10]; const float* bqf  = (const float*)d_in[11];
  const float* Wq2  = (const float*)d_in[12]; const float* bq2  = (const float*)d_in[13];
  const float* Wk2  = (const float*)d_in[14]; const float* bk2  = (const float*)d_in[15];
  const float* Wqf2 = (const float*)d_in[16]; const float* bqf2 = (const float*)d_in[17];
  const float* Wkf2 = (const float*)d_in[18]; const float* bkf2 = (const float*)d_in[19];
  const float* Wo   = (const float*)d_in[20]; const float* bo   = (const float*)d_in[21];

  u16* ws = (u16*)d_ws;
  u16* Wt = ws;                                   // 10 x 262144 u16 (5120x512)
  float* biasP = (float*)(ws + 2621440);          // 5120 f32
  u16* bufs = ws + 2621440 + 10240;
  const size_t BUF = 2097152;
  u16* v1  = bufs + 0 * BUF;
  u16* k1  = bufs + 1 * BUF;
  u16* q1  = bufs + 2 * BUF;   // later reused as vt
  u16* kf1 = bufs + 3 * BUF;   // later reused as att
  u16* qf1 = bufs + 4 * BUF;
  u16* q2  = bufs + 5 * BUF;   // first used as xb
  u16* k2  = bufs + 6 * BUF;   // first used as xkb
  u16* qf2 = bufs + 7 * BUF;
  u16* kf2 = bufs + 8 * BUF;

  cvt_bf16<<<dim3(1024, 2), 256, 0, stream>>>(x, xk, q2, k2);

  TPtrs tp;
  tp.p[0] = Wv;  tp.p[1] = Wk;  tp.p[2] = Wq;   tp.p[3] = Wkf;  tp.p[4] = Wqf;
  tp.p[5] = Wq2; tp.p[6] = Wk2; tp.p[7] = Wqf2; tp.p[8] = Wkf2; tp.p[9] = Wo;
  transposeW<<<dim3(8, 8, 10), 256, 0, stream>>>(tp, Wt);

  BPtrs bp;
  bp.p[0] = bv;  bp.p[1] = bk;  bp.p[2] = bq;   bp.p[3] = bkf;  bp.p[4] = bqf;
  bp.p[5] = bq2; bp.p[6] = bk2; bp.p[7] = bqf2; bp.p[8] = bkf2; bp.p[9] = bo;
  biasPack<<<dim3(10), 512, 0, stream>>>(bp, biasP);

  // stage-1 fused: x @ [Wv|Wk|Wq] -> v1,k1,q1
  GemmBatch g1 = {};
  g1.A[0] = q2;  g1.wrow0 = 0; g1.zstride = 0;
  g1.out[0][0] = v1; g1.out[0][1] = k1; g1.out[0][2] = q1;
  gemm3<u16><<<dim3(12, 32, 1), 256, 0, stream>>>(g1, Wt, biasP);

  // stage-1 fused: xk @ [Wkf|Wqf] -> kf1,qf1
  GemmBatch g2 = {};
  g2.A[0] = k2;  g2.wrow0 = 1536; g2.zstride = 0;
  g2.out[0][0] = kf1; g2.out[0][1] = qf1;
  gemm3<u16><<<dim3(8, 32, 1), 256, 0, stream>>>(g2, Wt, biasP);

  // stage-2 batched: {q1,k1,qf1,kf1} @ {Wq2,Wk2,Wqf2,Wkf2} -> {q2,k2,qf2,kf2}
  GemmBatch g3 = {};
  g3.A[0] = q1; g3.A[1] = k1; g3.A[2] = qf1; g3.A[3] = kf1;
  g3.wrow0 = 2560; g3.zstride = 512;
  g3.out[0][0] = q2; g3.out[1][0] = k2; g3.out[2][0] = qf2; g3.out[3][0] = kf2;
  gemm3<u16><<<dim3(4, 32, 4), 256, 0, stream>>>(g3, Wt, biasP);

  // V transpose per head (into q1 slot, dead after stage-2)
  transposeV<<<dim3(32, 16), 256, 0, stream>>>(v1, q1);

  // attention (att into kf1 slot, dead after stage-2)
  attn3<<<dim3(256), 256, 0, stream>>>(q2, k2, qf2, kf2, q1, kf1);

  // final: att @ Wo + bo -> d_out (fp32)
  GemmBatch g4 = {};
  g4.A[0] = kf1; g4.wrow0 = 4608; g4.zstride = 0;
  g4.out[0][0] = d_out;
  gemm3<float><<<dim3(4, 32, 1), 256, 0, stream>>>(g4, Wt, biasP);
}